// Round 1
// baseline (1079.587 us; speedup 1.0000x reference)
//
#include <hip/hip_runtime.h>
#include <stdint.h>

// B=8192, N=17, C=512, H=8, HD=64
// qkv = x@W_qkv + b_qkv                       [139264,1536]
// per (b,h): softmax((q k^T + alpha*outer)*0.125) @ v
// out = attn_out @ W_proj + b_proj            [139264,512] fp32

typedef __attribute__((ext_vector_type(4))) float f32x4;
typedef __attribute__((ext_vector_type(8))) short short8;

__device__ __forceinline__ unsigned short f2bf(float f) {
  uint32_t u = __builtin_bit_cast(uint32_t, f);
  u += 0x7fffu + ((u >> 16) & 1u);   // RNE
  return (unsigned short)(u >> 16);
}
__device__ __forceinline__ float bf2f(unsigned short h) {
  return __builtin_bit_cast(float, (uint32_t)h << 16);
}
__device__ __forceinline__ float bfdot2(uint32_t a, uint32_t b) {
  float al = __builtin_bit_cast(float, a << 16);
  float ah = __builtin_bit_cast(float, a & 0xffff0000u);
  float bl = __builtin_bit_cast(float, b << 16);
  float bh = __builtin_bit_cast(float, b & 0xffff0000u);
  return al * bl + ah * bh;
}

#define GLOAD_LDS16(gptr, lptr)                                          \
  __builtin_amdgcn_global_load_lds(                                      \
      (__attribute__((address_space(1))) void*)(gptr),                   \
      (__attribute__((address_space(3))) void*)(lptr), 16, 0, 0)

__device__ __forceinline__ f32x4 mfma16x16x32(short8 a, short8 b, f32x4 c) {
  return __builtin_amdgcn_mfma_f32_16x16x32_bf16(a, b, c, 0, 0, 0);
}

// ---------------- cast fp32 -> bf16, 4 elems/thread ----------------
__global__ __launch_bounds__(256) void k_cvt(const float* __restrict__ in,
                                             unsigned short* __restrict__ out,
                                             long n4) {
  long i = (long)blockIdx.x * 256 + threadIdx.x;
  if (i >= n4) return;
  float4 a = reinterpret_cast<const float4*>(in)[i];
  ushort4 o;
  o.x = f2bf(a.x); o.y = f2bf(a.y); o.z = f2bf(a.z); o.w = f2bf(a.w);
  reinterpret_cast<ushort4*>(out)[i] = o;
}

// ---------- transpose-cast W[K][N] fp32 -> Wt[N][K] bf16 ----------
__global__ __launch_bounds__(256) void k_cvt_t(const float* __restrict__ W,
                                               unsigned short* __restrict__ Wt,
                                               int K, int N) {
  int i = blockIdx.x * 256 + threadIdx.x;
  if (i >= K * N) return;
  int n = i / K, k = i - n * K;
  Wt[i] = f2bf(W[(size_t)k * N + n]);
}

// ---------------- GEMM: C = A[M][K] * Bt[N][K]^T + bias ----------------
// m97 structure: 128x128 tile, BK=64, 4 waves (2x2), 4x4 16x16 frags/wave,
// global_load_lds width 16, 2 barriers per K-step.
template <bool BF16OUT>
__global__ __launch_bounds__(256) void k_gemm_bt(
    const unsigned short* __restrict__ A,   // [M][K] bf16
    const unsigned short* __restrict__ Bt,  // [N][K] bf16
    const float* __restrict__ bias,         // [N]
    void* __restrict__ Cout,                // [M][N] bf16 or fp32
    int M, int N, int K) {
  __shared__ __align__(16) unsigned short As[128 * 64];
  __shared__ __align__(16) unsigned short Bs[128 * 64];

  const int tid = threadIdx.x;
  // bijective XCD swizzle (grid % 8 == 0): one XCD gets a contiguous chunk
  // of row-panels -> A panel fetched from HBM ~once.
  const int bid = (blockIdx.x & 7) * ((int)gridDim.x >> 3) + (blockIdx.x >> 3);
  const int nbn = N >> 7;
  const int brow = (bid / nbn) << 7;
  const int bcol = (bid % nbn) << 7;

  const int wid = tid >> 6, lane = tid & 63;
  const int wr = (wid >> 1) * 64, wc = (wid & 1) * 64;
  const int lr = lane & 15, lk = lane >> 4;

  f32x4 acc[4][4];
#pragma unroll
  for (int m = 0; m < 4; m++)
#pragma unroll
    for (int n = 0; n < 4; n++) acc[m][n] = f32x4{0.f, 0.f, 0.f, 0.f};

  // staging: thread t, chunk i: row = t/8 + 32*i, 16B segment (t%8)*8 elems
  const int srow = tid >> 3;
  const int sseg = (tid & 7) * 8;
  const unsigned short* Ag = A + (size_t)(brow + srow) * K + sseg;
  const unsigned short* Bg = Bt + (size_t)(bcol + srow) * K + sseg;
  unsigned short* Asl = As + tid * 8;  // linear: byte off = t*16 (+ i*4096)
  unsigned short* Bsl = Bs + tid * 8;
  const size_t rowstep = (size_t)32 * K;

  for (int k0 = 0; k0 < K; k0 += 64) {
#pragma unroll
    for (int i = 0; i < 4; i++)
      GLOAD_LDS16(Ag + k0 + i * rowstep, Asl + i * 2048);
#pragma unroll
    for (int i = 0; i < 4; i++)
      GLOAD_LDS16(Bg + k0 + i * rowstep, Bsl + i * 2048);
    __syncthreads();  // compiler drains vmcnt(0) before barrier

#pragma unroll
    for (int kk = 0; kk < 2; ++kk) {
      short8 af[4], bfr[4];
#pragma unroll
      for (int m = 0; m < 4; m++)
        af[m] = *reinterpret_cast<const short8*>(
            As + (wr + m * 16 + lr) * 64 + kk * 32 + lk * 8);
#pragma unroll
      for (int n = 0; n < 4; n++)
        bfr[n] = *reinterpret_cast<const short8*>(
            Bs + (wc + n * 16 + lr) * 64 + kk * 32 + lk * 8);
#pragma unroll
      for (int m = 0; m < 4; m++)
#pragma unroll
        for (int n = 0; n < 4; n++)
          acc[m][n] = mfma16x16x32(af[m], bfr[n], acc[m][n]);
    }
    __syncthreads();
  }

  // epilogue: C/D layout col = lane&15, row = (lane>>4)*4 + r   [m89/m91]
  const int orow0 = brow + wr + (lane >> 4) * 4;
#pragma unroll
  for (int n = 0; n < 4; n++) {
    const int col = bcol + wc + n * 16 + lr;
    const float bv = bias[col];
#pragma unroll
    for (int m = 0; m < 4; m++) {
      const int row = orow0 + m * 16;
#pragma unroll
      for (int r = 0; r < 4; r++) {
        float v = acc[m][n][r] + bv;
        if (BF16OUT)
          ((unsigned short*)Cout)[(size_t)(row + r) * N + col] = f2bf(v);
        else
          ((float*)Cout)[(size_t)(row + r) * N + col] = v;
      }
    }
  }
}

// ---------------- attention: one block per batch ----------------
// qkv row b*17+n, cols: q = h*64+d, k = 512+h*64+d, v = 1024+h*64+d
__global__ __launch_bounds__(256) void k_attn(
    const unsigned short* __restrict__ qkv,  // [B*17][1536] bf16
    const float* __restrict__ outer,         // [8][17][17]
    const float* __restrict__ alpha_p,       // [1]
    unsigned short* __restrict__ out) {      // [B*17][512] bf16
  __shared__ __align__(16) unsigned short sq[17 * 1536];
  __shared__ float sattn[4][17][18];

  const int b = blockIdx.x, tid = threadIdx.x;
  {
    const uint4* src = reinterpret_cast<const uint4*>(qkv + (size_t)b * 17 * 1536);
    uint4* dst = reinterpret_cast<uint4*>(sq);
    for (int i = tid; i < 17 * 1536 / 8; i += 256) dst[i] = src[i];
  }
  __syncthreads();

  const float alpha = alpha_p[0];
  const float scale = 0.125f;  // 64^-0.5
  const int wid = tid >> 6, lane = tid & 63;

  for (int hh = 0; hh < 2; ++hh) {
    const int h = wid * 2 + hh;
    // logits: lane owns (r,m) pairs p, p+64, ... < 289
    for (int p = lane; p < 289; p += 64) {
      const int r = p / 17, m = p - r * 17;
      const uint4* qr = reinterpret_cast<const uint4*>(sq + r * 1536 + h * 64);
      const uint4* km = reinterpret_cast<const uint4*>(sq + m * 1536 + 512 + h * 64);
      float acc = 0.f;
#pragma unroll
      for (int c = 0; c < 8; c++) {
        uint4 qa = qr[c], ka = km[c];
        acc += bfdot2(qa.x, ka.x) + bfdot2(qa.y, ka.y) +
               bfdot2(qa.z, ka.z) + bfdot2(qa.w, ka.w);
      }
      sattn[wid][r][m] = (acc + alpha * outer[h * 289 + p]) * scale;
    }
    __syncthreads();

    // softmax rows: lanes 0..16
    if (lane < 17) {
      float mx = -1e30f;
#pragma unroll
      for (int m = 0; m < 17; m++) mx = fmaxf(mx, sattn[wid][lane][m]);
      float s = 0.f;
#pragma unroll
      for (int m = 0; m < 17; m++) {
        float e = __expf(sattn[wid][lane][m] - mx);
        sattn[wid][lane][m] = e;
        s += e;
      }
      float inv = 1.f / s;
#pragma unroll
      for (int m = 0; m < 17; m++) sattn[wid][lane][m] *= inv;
    }
    __syncthreads();

    // PV: lane = output column d, loop rows
    float vreg[17];
#pragma unroll
    for (int m = 0; m < 17; m++)
      vreg[m] = bf2f(sq[m * 1536 + 1024 + h * 64 + lane]);
#pragma unroll 1
    for (int r = 0; r < 17; r++) {
      float acc = 0.f;
#pragma unroll
      for (int m = 0; m < 17; m++) acc += sattn[wid][r][m] * vreg[m];
      out[((size_t)b * 17 + r) * 512 + h * 64 + lane] = f2bf(acc);
    }
    __syncthreads();
  }
}

// ---------------- launch ----------------
extern "C" void kernel_launch(void* const* d_in, const int* in_sizes, int n_in,
                              void* d_out, int out_size, void* d_ws,
                              size_t ws_size, hipStream_t stream) {
  const float* x      = (const float*)d_in[0];
  const float* W_qkv  = (const float*)d_in[1];
  const float* b_qkv  = (const float*)d_in[2];
  const float* outer  = (const float*)d_in[3];
  const float* alpha  = (const float*)d_in[4];
  const float* W_proj = (const float*)d_in[5];
  const float* b_proj = (const float*)d_in[6];

  // workspace layout (bytes), total 572,522,496
  char* ws = (char*)d_ws;
  unsigned short* xb  = (unsigned short*)(ws);              // 142,606,336 (also reused as attn_out)
  unsigned short* qkv = (unsigned short*)(ws + 142606336);  // 427,819,008
  unsigned short* wqt = (unsigned short*)(ws + 570425344);  // 1,572,864
  unsigned short* wpt = (unsigned short*)(ws + 571998208);  // 524,288

  // 1) casts
  k_cvt<<<dim3(69632), dim3(256), 0, stream>>>(x, xb, 17825792L);
  k_cvt_t<<<dim3(3072), dim3(256), 0, stream>>>(W_qkv, wqt, 512, 1536);
  k_cvt_t<<<dim3(1024), dim3(256), 0, stream>>>(W_proj, wpt, 512, 512);
  // 2) qkv GEMM  (139264/128=1088 row tiles, 1536/128=12 col tiles)
  k_gemm_bt<true><<<dim3(13056), dim3(256), 0, stream>>>(
      xb, wqt, b_qkv, qkv, 139264, 1536, 512);
  // 3) attention (writes into xb, which is dead now)
  k_attn<<<dim3(8192), dim3(256), 0, stream>>>(qkv, outer, alpha, xb);
  // 4) proj GEMM -> fp32 d_out  (512/128=4 col tiles)
  k_gemm_bt<false><<<dim3(4352), dim3(256), 0, stream>>>(
      xb, wpt, b_proj, (float*)d_out, 139264, 512, 512);
}

// Round 2
// 826.592 us; speedup vs baseline: 1.3061x; 1.3061x over previous
//
#include <hip/hip_runtime.h>
#include <stdint.h>

// B=8192, N=17, C=512, H=8, HD=64  — full pipeline in f16 (inputs fp32)

typedef __attribute__((ext_vector_type(4))) float f32x4;
typedef _Float16 f16x8 __attribute__((ext_vector_type(8)));
typedef _Float16 f16x2 __attribute__((ext_vector_type(2)));

__device__ __forceinline__ unsigned short f2h(float f) {
  return __builtin_bit_cast(unsigned short, (_Float16)f);
}
__device__ __forceinline__ float h2f(unsigned short h) {
  return (float)__builtin_bit_cast(_Float16, h);
}
__device__ __forceinline__ float fdot2u(uint32_t a, uint32_t b, float c) {
#if __has_builtin(__builtin_amdgcn_fdot2)
  return __builtin_amdgcn_fdot2(__builtin_bit_cast(f16x2, a),
                                __builtin_bit_cast(f16x2, b), c, false);
#else
  f16x2 A = __builtin_bit_cast(f16x2, a), B = __builtin_bit_cast(f16x2, b);
  return c + (float)A[0] * (float)B[0] + (float)A[1] * (float)B[1];
#endif
}

#define GLOAD_LDS16(gptr, lptr)                                          \
  __builtin_amdgcn_global_load_lds(                                      \
      (__attribute__((address_space(1))) void*)(gptr),                   \
      (__attribute__((address_space(3))) void*)(lptr), 16, 0, 0)

__device__ __forceinline__ f32x4 mfma16(f16x8 a, f16x8 b, f32x4 c) {
  return __builtin_amdgcn_mfma_f32_16x16x32_f16(a, b, c, 0, 0, 0);
}

// ---------------- cast fp32 -> f16, 4 elems/thread ----------------
__global__ __launch_bounds__(256) void k_cvt(const float* __restrict__ in,
                                             unsigned short* __restrict__ out,
                                             long n4) {
  long i = (long)blockIdx.x * 256 + threadIdx.x;
  if (i >= n4) return;
  float4 a = reinterpret_cast<const float4*>(in)[i];
  ushort4 o;
  o.x = f2h(a.x); o.y = f2h(a.y); o.z = f2h(a.z); o.w = f2h(a.w);
  reinterpret_cast<ushort4*>(out)[i] = o;
}

// ---------- transpose-cast W[K][N] fp32 -> Wt[N][K] f16 ----------
__global__ __launch_bounds__(256) void k_cvt_t(const float* __restrict__ W,
                                               unsigned short* __restrict__ Wt,
                                               int K, int N) {
  int i = blockIdx.x * 256 + threadIdx.x;
  if (i >= K * N) return;
  int n = i / K, k = i - n * K;
  Wt[i] = f2h(W[(size_t)k * N + n]);
}

// ---------------- GEMM: C = A[M][K] * Bt[N][K]^T + bias ----------------
// m97 structure: 128x128 tile, BK=64, 4 waves (2x2), 4x4 16x16 frags/wave.
template <bool F16OUT>
__global__ __launch_bounds__(256) void k_gemm_bt(
    const unsigned short* __restrict__ A,   // [M][K] f16
    const unsigned short* __restrict__ Bt,  // [N][K] f16
    const float* __restrict__ bias,         // [N]
    void* __restrict__ Cout,                // [M][N] f16 or fp32
    int M, int N, int K) {
  __shared__ __align__(16) unsigned short As[128 * 64];
  __shared__ __align__(16) unsigned short Bs[128 * 64];

  const int tid = threadIdx.x;
  const int bid = (blockIdx.x & 7) * ((int)gridDim.x >> 3) + (blockIdx.x >> 3);
  const int nbn = N >> 7;
  const int brow = (bid / nbn) << 7;
  const int bcol = (bid % nbn) << 7;

  const int wid = tid >> 6, lane = tid & 63;
  const int wr = (wid >> 1) * 64, wc = (wid & 1) * 64;
  const int lr = lane & 15, lk = lane >> 4;

  f32x4 acc[4][4];
#pragma unroll
  for (int m = 0; m < 4; m++)
#pragma unroll
    for (int n = 0; n < 4; n++) acc[m][n] = f32x4{0.f, 0.f, 0.f, 0.f};

  const int srow = tid >> 3;
  const int sseg = (tid & 7) * 8;
  const unsigned short* Ag = A + (size_t)(brow + srow) * K + sseg;
  const unsigned short* Bg = Bt + (size_t)(bcol + srow) * K + sseg;
  unsigned short* Asl = As + tid * 8;
  unsigned short* Bsl = Bs + tid * 8;
  const size_t rowstep = (size_t)32 * K;

  for (int k0 = 0; k0 < K; k0 += 64) {
#pragma unroll
    for (int i = 0; i < 4; i++)
      GLOAD_LDS16(Ag + k0 + i * rowstep, Asl + i * 2048);
#pragma unroll
    for (int i = 0; i < 4; i++)
      GLOAD_LDS16(Bg + k0 + i * rowstep, Bsl + i * 2048);
    __syncthreads();

#pragma unroll
    for (int kk = 0; kk < 2; ++kk) {
      f16x8 af[4], bfr[4];
#pragma unroll
      for (int m = 0; m < 4; m++)
        af[m] = *reinterpret_cast<const f16x8*>(
            As + (wr + m * 16 + lr) * 64 + kk * 32 + lk * 8);
#pragma unroll
      for (int n = 0; n < 4; n++)
        bfr[n] = *reinterpret_cast<const f16x8*>(
            Bs + (wc + n * 16 + lr) * 64 + kk * 32 + lk * 8);
#pragma unroll
      for (int m = 0; m < 4; m++)
#pragma unroll
        for (int n = 0; n < 4; n++)
          acc[m][n] = mfma16(af[m], bfr[n], acc[m][n]);
    }
    __syncthreads();
  }

  const int orow0 = brow + wr + (lane >> 4) * 4;
#pragma unroll
  for (int n = 0; n < 4; n++) {
    const int col = bcol + wc + n * 16 + lr;
    const float bv = bias[col];
#pragma unroll
    for (int m = 0; m < 4; m++) {
      const int row = orow0 + m * 16;
#pragma unroll
      for (int r = 0; r < 4; r++) {
        float v = acc[m][n][r] + bv;
        if (F16OUT)
          ((unsigned short*)Cout)[(size_t)(row + r) * N + col] = f2h(v);
        else
          ((float*)Cout)[(size_t)(row + r) * N + col] = v;
      }
    }
  }
}

// ---------------- attention: one block per batch, wave-local phases -------
// sq stages q,k only, padded row stride 1032 shorts (516 words ≡ 4 mod 32).
#define SQS4 129  // uint4 per padded row
__global__ __launch_bounds__(256) void k_attn(
    const unsigned short* __restrict__ qkv,  // [B*17][1536] f16
    const float* __restrict__ outer,         // [8][17][17]
    const float* __restrict__ alpha_p,       // [1]
    unsigned short* __restrict__ out) {      // [B*17][512] f16
  __shared__ __align__(16) uint4 sq4[17 * SQS4];
  __shared__ float sattn[4][17][18];
  __shared__ float sinv[4][17];

  const int b = blockIdx.x, tid = threadIdx.x;
  {
    const uint4* src = reinterpret_cast<const uint4*>(qkv + (size_t)b * 17 * 1536);
    for (int i = tid; i < 17 * 128; i += 256) {
      int row = i >> 7, seg = i & 127;
      sq4[row * SQS4 + seg] = src[row * 192 + seg];
    }
  }
  __syncthreads();

  const unsigned short* sq = (const unsigned short*)sq4;
  const float alpha = alpha_p[0];
  const int wid = tid >> 6, lane = tid & 63;

  for (int hh = 0; hh < 2; ++hh) {
    const int h = wid * 2 + hh;
    // logits: lane owns (r,m) = p/17, p%17.  q-side: ~4 addrs (broadcast);
    // k-side: 17 addrs over 8 bank-groups (<=3-way).
    for (int p = lane; p < 289; p += 64) {
      const int r = p / 17, m = p - r * 17;
      const uint4* qr = reinterpret_cast<const uint4*>(sq + r * 1032 + h * 64);
      const uint4* km = reinterpret_cast<const uint4*>(sq + m * 1032 + 512 + h * 64);
      float acc = 0.f;
#pragma unroll
      for (int c = 0; c < 8; c++) {
        uint4 qa = qr[c], ka = km[c];
        acc = fdot2u(qa.x, ka.x, acc);
        acc = fdot2u(qa.y, ka.y, acc);
        acc = fdot2u(qa.z, ka.z, acc);
        acc = fdot2u(qa.w, ka.w, acc);
      }
      sattn[wid][r][m] = (acc + alpha * outer[h * 289 + p]) * 0.125f;
    }
    __builtin_amdgcn_wave_barrier();
    asm volatile("" ::: "memory");  // same-wave DS ops complete in order

    if (lane < 17) {
      float mx = -1e30f;
#pragma unroll
      for (int m = 0; m < 17; m++) mx = fmaxf(mx, sattn[wid][lane][m]);
      float s = 0.f;
#pragma unroll
      for (int m = 0; m < 17; m++) {
        float e = __expf(sattn[wid][lane][m] - mx);
        sattn[wid][lane][m] = e;
        s += e;
      }
      sinv[wid][lane] = 1.f / s;  // normalize folded into PV
    }
    __builtin_amdgcn_wave_barrier();
    asm volatile("" ::: "memory");

    // PV: lane = output dim d; v straight from global (coalesced 128B rows)
    float vr[17];
#pragma unroll
    for (int m = 0; m < 17; m++)
      vr[m] = h2f(qkv[((size_t)b * 17 + m) * 1536 + 1024 + h * 64 + lane]);
#pragma unroll 1
    for (int r = 0; r < 17; r++) {
      float acc = 0.f;
#pragma unroll
      for (int m = 0; m < 17; m++) acc += sattn[wid][r][m] * vr[m];
      out[((size_t)b * 17 + r) * 512 + h * 64 + lane] = f2h(acc * sinv[wid][r]);
    }
    __builtin_amdgcn_wave_barrier();
    asm volatile("" ::: "memory");
  }
}

// ---------------- launch ----------------
extern "C" void kernel_launch(void* const* d_in, const int* in_sizes, int n_in,
                              void* d_out, int out_size, void* d_ws,
                              size_t ws_size, hipStream_t stream) {
  const float* x      = (const float*)d_in[0];
  const float* W_qkv  = (const float*)d_in[1];
  const float* b_qkv  = (const float*)d_in[2];
  const float* outer  = (const float*)d_in[3];
  const float* alpha  = (const float*)d_in[4];
  const float* W_proj = (const float*)d_in[5];
  const float* b_proj = (const float*)d_in[6];

  char* ws = (char*)d_ws;
  unsigned short* xb  = (unsigned short*)(ws);              // 142,606,336 (reused as attn_out)
  unsigned short* qkv = (unsigned short*)(ws + 142606336);  // 427,819,008
  unsigned short* wqt = (unsigned short*)(ws + 570425344);  // 1,572,864
  unsigned short* wpt = (unsigned short*)(ws + 571998208);  // 524,288

  k_cvt<<<dim3(69632), dim3(256), 0, stream>>>(x, xb, 17825792L);
  k_cvt_t<<<dim3(3072), dim3(256), 0, stream>>>(W_qkv, wqt, 512, 1536);
  k_cvt_t<<<dim3(1024), dim3(256), 0, stream>>>(W_proj, wpt, 512, 512);
  k_gemm_bt<true><<<dim3(13056), dim3(256), 0, stream>>>(
      xb, wqt, b_qkv, qkv, 139264, 1536, 512);
  k_attn<<<dim3(8192), dim3(256), 0, stream>>>(qkv, outer, alpha, xb);
  k_gemm_bt<false><<<dim3(4352), dim3(256), 0, stream>>>(
      xb, wpt, b_proj, (float*)d_out, 139264, 512, 512);
}